// Round 1
// baseline (774.701 us; speedup 1.0000x reference)
//
#include <hip/hip_runtime.h>

typedef __bf16 bf16x8 __attribute__((ext_vector_type(8)));
typedef float floatx4 __attribute__((ext_vector_type(4)));
typedef unsigned short ushort_t;
typedef unsigned short ushortx8 __attribute__((ext_vector_type(8)));

// fp32 -> bf16 round-to-nearest-even
__device__ inline ushort_t f2bf(float f) {
    union { float f; unsigned int u; } v; v.f = f;
    unsigned int u = v.u;
    unsigned int r = (u + 0x7FFFu + ((u >> 16) & 1u)) >> 16;
    return (ushort_t)r;
}

__device__ inline float gelu_f(float x) {
    return 0.5f * x * (1.0f + erff(x * 0.70710678118654752f));
}

// ---------------------------------------------------------------------------
// Pack W1/W2/W3 (fp32 row-major [K][N]) into bf16 MFMA B-fragment order:
// frag(nt, ks): lane holds B[32*ks + 8*(lane>>4) + j][16*nt + (lane&15)], j=0..7
// flat offset = ((nt*Ksteps + ks)*64 + lane)*8, m-major blocks.
// Totals (segs of 8): L1 2*24*12*64=36864, L2 2*12*12*64=18432, L3 2*6*6*64=4608
// ---------------------------------------------------------------------------
__global__ __launch_bounds__(256) void pack_weights(
    const float* __restrict__ W1, const float* __restrict__ W2,
    const float* __restrict__ W3, ushort_t* __restrict__ wsp)
{
    int g = blockIdx.x * 256 + threadIdx.x;
    if (g >= 59904) return;
    const float* src; int N; int nt, ks, lane; ushort_t* dst;
    if (g < 36864) {                       // W1: K=384,N=384
        int m = g / 18432, r = g % 18432;
        src = W1 + m * 147456; N = 384;
        nt = r / 768; int r2 = r % 768; ks = r2 / 64; lane = r2 % 64;
        dst = wsp + (size_t)g * 8;
    } else if (g < 55296) {                // W2: K=384,N=192
        int g2 = g - 36864;
        int m = g2 / 9216, r = g2 % 9216;
        src = W2 + m * 73728; N = 192;
        nt = r / 768; int r2 = r % 768; ks = r2 / 64; lane = r2 % 64;
        dst = wsp + 294912 + (size_t)g2 * 8;
    } else {                               // W3: K=192,N=96
        int g3 = g - 55296;
        int m = g3 / 2304, r = g3 % 2304;
        src = W3 + m * 18432; N = 96;
        nt = r / 384; int r2 = r % 384; ks = r2 / 64; lane = r2 % 64;
        dst = wsp + 442368 + (size_t)g3 * 8;
    }
    int q = lane >> 4, l16 = lane & 15;
    int kbase = 32 * ks + 8 * q;
    int n = 16 * nt + l16;
    ushortx8 o;
    #pragma unroll
    for (int j = 0; j < 8; ++j) o[j] = f2bf(src[(size_t)(kbase + j) * N + n]);
    *(ushortx8*)dst = o;
}

// ---------------------------------------------------------------------------
// Fused: LN -> GEMM1(384x384)+GELU -> GEMM2(384x192)+GELU -> GEMM3(192x96)+GELU
//        -> GEMM4(96x2) -> log_softmax.  One block = 32 rows, 256 thr (4 waves).
// LDS strides padded +8 bf16 so ds_read_b128 A-frags cover all 32 banks.
// ---------------------------------------------------------------------------
__global__ __launch_bounds__(256, 3) void fused_mlp(
    const float* __restrict__ x, const float* __restrict__ ln_g, const float* __restrict__ ln_b,
    const float* __restrict__ b1, const float* __restrict__ b2, const float* __restrict__ b3,
    const float* __restrict__ W4, const float* __restrict__ b4,
    const ushort_t* __restrict__ wsp, float* __restrict__ out)
{
    __shared__ ushort_t sA[12544];   // 32 x stride392 bf16 (also reused: 32 x stride200)
    __shared__ ushort_t sH[12544];   // 32 x stride392 bf16 (also reused: 32 x stride104)
    __shared__ float    sF[864];     // b1[0,384) b2[384,576) b3[576,672) W4T[672,864)

    const int tid = threadIdx.x;
    const int w = tid >> 6, lane = tid & 63, q = lane >> 4, l16 = lane & 15;
    const int bid = blockIdx.x;
    const int m  = bid >> 12;        // 4096 row-blocks per modality
    const int rb = bid & 4095;
    const size_t row0 = (size_t)m * 131072 + (size_t)rb * 32;

    // ---- stage biases + W4^T into LDS ----
    {
        const float* pb1 = b1 + m * 384;
        const float* pb2 = b2 + m * 192;
        const float* pb3 = b3 + m * 96;
        const float* pW4 = W4 + m * 192;
        for (int i = tid; i < 384; i += 256) sF[i] = pb1[i];
        if (tid < 192) sF[384 + tid] = pb2[tid];
        if (tid < 96)  sF[576 + tid] = pb3[tid];
        if (tid < 192) sF[672 + (tid & 1) * 96 + (tid >> 1)] = pW4[tid]; // W4T[cl][k]
    }

    // ---- LayerNorm: 8 threads/row, 48 cols each; bf16 -> sA stride 392 ----
    {
        const int row = tid >> 3, j = tid & 7;
        const float4* xv = (const float4*)(x + (row0 + row) * 384);
        const float4* gv = (const float4*)(ln_g + m * 384);
        const float4* bv = (const float4*)(ln_b + m * 384);
        float vals[48];
        float s = 0.f, s2 = 0.f;
        #pragma unroll
        for (int i = 0; i < 12; ++i) {
            float4 f = xv[j * 12 + i];
            vals[4*i+0] = f.x; vals[4*i+1] = f.y; vals[4*i+2] = f.z; vals[4*i+3] = f.w;
            s  += f.x + f.y + f.z + f.w;
            s2 += f.x*f.x + f.y*f.y + f.z*f.z + f.w*f.w;
        }
        s  += __shfl_xor(s, 1);  s  += __shfl_xor(s, 2);  s  += __shfl_xor(s, 4);
        s2 += __shfl_xor(s2, 1); s2 += __shfl_xor(s2, 2); s2 += __shfl_xor(s2, 4);
        const float mu   = s * (1.0f / 384.0f);
        const float var  = s2 * (1.0f / 384.0f) - mu * mu;
        const float rstd = rsqrtf(var + 1e-5f);
        #pragma unroll
        for (int h = 0; h < 6; ++h) {
            float4 g0 = gv[j*12 + 2*h], g1 = gv[j*12 + 2*h + 1];
            float4 c0 = bv[j*12 + 2*h], c1 = bv[j*12 + 2*h + 1];
            ushortx8 o;
            o[0] = f2bf((vals[8*h+0]-mu)*rstd*g0.x + c0.x);
            o[1] = f2bf((vals[8*h+1]-mu)*rstd*g0.y + c0.y);
            o[2] = f2bf((vals[8*h+2]-mu)*rstd*g0.z + c0.z);
            o[3] = f2bf((vals[8*h+3]-mu)*rstd*g0.w + c0.w);
            o[4] = f2bf((vals[8*h+4]-mu)*rstd*g1.x + c1.x);
            o[5] = f2bf((vals[8*h+5]-mu)*rstd*g1.y + c1.y);
            o[6] = f2bf((vals[8*h+6]-mu)*rstd*g1.z + c1.z);
            o[7] = f2bf((vals[8*h+7]-mu)*rstd*g1.w + c1.w);
            *(ushortx8*)&sA[row * 392 + j * 48 + h * 8] = o;
        }
    }
    __syncthreads();

    const floatx4 vzero = {0.f, 0.f, 0.f, 0.f};

    // ---- Layer 1: [32x384] @ [384x384], wave w -> cols [96w, 96w+96) ----
    floatx4 acc1[2][6];
    #pragma unroll
    for (int rt = 0; rt < 2; ++rt)
        #pragma unroll
        for (int ct = 0; ct < 6; ++ct) acc1[rt][ct] = vzero;
    {
        const bf16x8* Bv = (const bf16x8*)(wsp + m * 147456) + (size_t)(6 * w) * 12 * 64 + lane;
        #pragma unroll 3
        for (int ks = 0; ks < 12; ++ks) {
            bf16x8 a0 = *(const bf16x8*)&sA[l16        * 392 + 32 * ks + 8 * q];
            bf16x8 a1 = *(const bf16x8*)&sA[(16 + l16) * 392 + 32 * ks + 8 * q];
            #pragma unroll
            for (int ct = 0; ct < 6; ++ct) {
                bf16x8 b = Bv[(ct * 12 + ks) * 64];
                acc1[0][ct] = __builtin_amdgcn_mfma_f32_16x16x32_bf16(a0, b, acc1[0][ct], 0, 0, 0);
                acc1[1][ct] = __builtin_amdgcn_mfma_f32_16x16x32_bf16(a1, b, acc1[1][ct], 0, 0, 0);
            }
        }
    }
    #pragma unroll
    for (int ct = 0; ct < 6; ++ct) {
        const int col = 96 * w + 16 * ct + l16;
        const float bb = sF[col];
        #pragma unroll
        for (int rt = 0; rt < 2; ++rt)
            #pragma unroll
            for (int i = 0; i < 4; ++i) {
                const int row = 16 * rt + 4 * q + i;
                sH[row * 392 + col] = f2bf(gelu_f(acc1[rt][ct][i] + bb));
            }
    }
    __syncthreads();

    // ---- Layer 2: [32x384] @ [384x192], wave w -> cols [48w, 48w+48) ----
    floatx4 acc2[2][3];
    #pragma unroll
    for (int rt = 0; rt < 2; ++rt)
        #pragma unroll
        for (int ct = 0; ct < 3; ++ct) acc2[rt][ct] = vzero;
    {
        const bf16x8* Bv = (const bf16x8*)(wsp + 294912 + m * 73728) + (size_t)(3 * w) * 12 * 64 + lane;
        #pragma unroll 3
        for (int ks = 0; ks < 12; ++ks) {
            bf16x8 a0 = *(const bf16x8*)&sH[l16        * 392 + 32 * ks + 8 * q];
            bf16x8 a1 = *(const bf16x8*)&sH[(16 + l16) * 392 + 32 * ks + 8 * q];
            #pragma unroll
            for (int ct = 0; ct < 3; ++ct) {
                bf16x8 b = Bv[(ct * 12 + ks) * 64];
                acc2[0][ct] = __builtin_amdgcn_mfma_f32_16x16x32_bf16(a0, b, acc2[0][ct], 0, 0, 0);
                acc2[1][ct] = __builtin_amdgcn_mfma_f32_16x16x32_bf16(a1, b, acc2[1][ct], 0, 0, 0);
            }
        }
    }
    #pragma unroll
    for (int ct = 0; ct < 3; ++ct) {
        const int col = 48 * w + 16 * ct + l16;          // < 192
        const float bb = sF[384 + col];
        #pragma unroll
        for (int rt = 0; rt < 2; ++rt)
            #pragma unroll
            for (int i = 0; i < 4; ++i) {
                const int row = 16 * rt + 4 * q + i;
                sA[row * 200 + col] = f2bf(gelu_f(acc2[rt][ct][i] + bb));
            }
    }
    __syncthreads();

    // ---- Layer 3: [32x192] @ [192x96]; wave w -> row-tile (w>>1), col-tiles 3*(w&1)+{0..2}
    floatx4 acc3[3];
    #pragma unroll
    for (int ct = 0; ct < 3; ++ct) acc3[ct] = vzero;
    {
        const int rt3 = w >> 1, cb = 3 * (w & 1);
        const bf16x8* Bv = (const bf16x8*)(wsp + 442368 + m * 18432) + lane;
        #pragma unroll
        for (int ks = 0; ks < 6; ++ks) {
            bf16x8 a = *(const bf16x8*)&sA[(16 * rt3 + l16) * 200 + 32 * ks + 8 * q];
            #pragma unroll
            for (int ct = 0; ct < 3; ++ct) {
                bf16x8 b = Bv[(size_t)((cb + ct) * 6 + ks) * 64];
                acc3[ct] = __builtin_amdgcn_mfma_f32_16x16x32_bf16(a, b, acc3[ct], 0, 0, 0);
            }
        }
        #pragma unroll
        for (int ct = 0; ct < 3; ++ct) {
            const int col = 16 * (cb + ct) + l16;        // < 96
            const float bb = sF[576 + col];
            #pragma unroll
            for (int i = 0; i < 4; ++i) {
                const int row = 16 * rt3 + 4 * q + i;
                sH[row * 104 + col] = f2bf(gelu_f(acc3[ct][i] + bb));
            }
        }
    }
    __syncthreads();

    // ---- Layer 4: [32x96] @ [96x2] + log_softmax; 128 threads, split-K ----
    if (tid < 128) {
        const int cl = tid & 1, kh = (tid >> 1) & 1, row = tid >> 2;
        const float* wv = &sF[672 + cl * 96 + kh * 48];
        float p = 0.f;
        #pragma unroll
        for (int kk = 0; kk < 6; ++kk) {
            bf16x8 h = *(const bf16x8*)&sH[row * 104 + kh * 48 + kk * 8];
            const float4 wa = *(const float4*)&wv[kk * 8];
            const float4 wb = *(const float4*)&wv[kk * 8 + 4];
            p += (float)h[0] * wa.x + (float)h[1] * wa.y + (float)h[2] * wa.z + (float)h[3] * wa.w
               + (float)h[4] * wb.x + (float)h[5] * wb.y + (float)h[6] * wb.z + (float)h[7] * wb.w;
        }
        p += __shfl_xor(p, 2);                  // combine K-halves
        const float logit = p + b4[m * 2 + cl];
        const float other = __shfl_xor(logit, 1);
        const float mx = fmaxf(logit, other);
        const float z  = expf(logit - mx) + expf(other - mx);
        const float res = logit - mx - logf(z);
        if (kh == 0) out[(row0 + row) * 2 + cl] = res;
    }
}

extern "C" void kernel_launch(void* const* d_in, const int* in_sizes, int n_in,
                              void* d_out, int out_size, void* d_ws, size_t ws_size,
                              hipStream_t stream)
{
    const float* x    = (const float*)d_in[0];
    const float* ln_g = (const float*)d_in[1];
    const float* ln_b = (const float*)d_in[2];
    const float* W1   = (const float*)d_in[3];
    const float* b1   = (const float*)d_in[4];
    const float* W2   = (const float*)d_in[5];
    const float* b2   = (const float*)d_in[6];
    const float* W3   = (const float*)d_in[7];
    const float* b3   = (const float*)d_in[8];
    const float* W4   = (const float*)d_in[9];
    const float* b4   = (const float*)d_in[10];
    float* out = (float*)d_out;
    ushort_t* wsp = (ushort_t*)d_ws;   // needs 958,464 B for packed bf16 weights

    pack_weights<<<234, 256, 0, stream>>>(W1, W2, W3, wsp);
    fused_mlp<<<8192, 256, 0, stream>>>(x, ln_g, ln_b, b1, b2, b3, W4, b4, wsp, out);
}